// Round 4
// baseline (324.124 us; speedup 1.0000x reference)
//
#include <hip/hip_runtime.h>

// image2patch: out[b, i*126+j, r*6+c] = x[b, 0, 2*i + r, 2*j + c]
// IMAGE_SIZE=256, PSIZE=6, STRIDE=2, NPOS=126, BATCH=128, fp32.
//
// R4 = R3 with the nontemporal-store type fixed (clang builtin needs a
// native vector type, not HIP's float4 wrapper class).
// (a) 4 patch-rows (bands) per block -> stage 12 image rows once instead
// of 4x6 (halves global reads + staging instrs + barriers); (b) LDS stride
// 256 (16B aligned) so staging is ds_write_b128; gather aliasing ~3-way
// (cheap per m136); (c) nontemporal output stores so the 292.6 MB stream
// doesn't evict the cached input rows from L2.

#define IMG 256
#define PSZ 6
#define NPOS 126
#define BATCHN 128
#define NB 4                       // bands (patch-rows) per block
#define NGROUPS 32                 // ceil(126/4)
#define TROWS (2 * NB + 4)         // 12 image rows staged
#define VECS_PER_BAND 1134         // 126 patches * 36 floats / 4

typedef float fvec4 __attribute__((ext_vector_type(4)));

__global__ __launch_bounds__(256) void image2patch_kernel(
    const float* __restrict__ x, float* __restrict__ out) {
  __shared__ float tile[TROWS * IMG];   // 12 KB, stride 256 (16B-aligned rows)

  const int blk = blockIdx.x;           // b * 32 + g
  const int b = blk >> 5;
  const int g = blk & 31;
  const int i0 = g * NB;                // first band; last group has only 2 valid
  const int t = threadIdx.x;

  // ---- stage image rows 2*i0 .. 2*i0+11 (clamped) via float4, b128 both sides ----
  const float* src = x + (size_t)b * (IMG * IMG);
  for (int idx = t; idx < TROWS * (IMG / 4); idx += 256) {   // 768 = 3 full iters
    const int row  = idx >> 6;          // 64 float4 per image row
    const int col4 = idx & 63;
    const int grow = 2 * i0 + row;
    if (grow < IMG) {
      fvec4 v = reinterpret_cast<const fvec4*>(src + (size_t)grow * IMG)[col4];
      reinterpret_cast<fvec4*>(&tile[row * IMG])[col4] = v;
    }
  }
  __syncthreads();

  // ---- emit NB bands: per band 1134 coalesced float4 nt-stores, LDS gather ----
  for (int band = 0; band < NB; ++band) {
    const int i = i0 + band;
    if (i >= NPOS) break;
    fvec4* outp = reinterpret_cast<fvec4*>(
        out + ((size_t)b * (NPOS * NPOS) + (size_t)i * NPOS) * (PSZ * PSZ));
    const int rbase = 2 * band;         // tile row of this band's image row 2i
    for (int q = t; q < VECS_PER_BAND; q += 256) {
      const int f  = q * 4;             // flat float index in the band
      const int j  = f / 36;            // patch column
      const int k0 = f - j * 36;        // 0,4,...,32
      const int col = 2 * j;
      fvec4 v;
      { const int k = k0;     const int r = k / PSZ, c = k - PSZ * r; v.x = tile[(rbase + r) * IMG + col + c]; }
      { const int k = k0 + 1; const int r = k / PSZ, c = k - PSZ * r; v.y = tile[(rbase + r) * IMG + col + c]; }
      { const int k = k0 + 2; const int r = k / PSZ, c = k - PSZ * r; v.z = tile[(rbase + r) * IMG + col + c]; }
      { const int k = k0 + 3; const int r = k / PSZ, c = k - PSZ * r; v.w = tile[(rbase + r) * IMG + col + c]; }
      __builtin_nontemporal_store(v, &outp[q]);
    }
  }
}

extern "C" void kernel_launch(void* const* d_in, const int* in_sizes, int n_in,
                              void* d_out, int out_size, void* d_ws, size_t ws_size,
                              hipStream_t stream) {
  const float* x = (const float*)d_in[0];
  float* out = (float*)d_out;
  image2patch_kernel<<<BATCHN * NGROUPS, 256, 0, stream>>>(x, out);
}

// Round 5
// 319.778 us; speedup vs baseline: 1.0136x; 1.0136x over previous
//
#include <hip/hip_runtime.h>

// image2patch: out[b, i*126+j, r*6+c] = x[b, 0, 2*i + r, 2*j + c]
// IMAGE_SIZE=256, PSIZE=6, STRIDE=2, NPOS=126, BATCH=128, fp32.
//
// R5: hot-loop has ZERO index math. Per-thread gather offsets (j, k->r,c)
// are band-independent -> precomputed once, reused across 6 bands/block
// (126 = 6*21 exactly; staged rows 12g..12g+15 tile the image exactly).
// Staging: thread t copies element t of each of 16 rows (coalesced 256B/wave
// reads, LDS bank = lane%32 -> conflict-free). Gather stride 257 (mixed
// parity banks, ~2.8-way = cheap per m136). No nontemporal (R4 regression).

#define IMG 256
#define PSZ 6
#define NPOS 126
#define BATCHN 128
#define NB 6                        // bands (patch-rows) per block
#define NGROUPS 21                  // 126 / 6, exact
#define TROWS 16                    // 2*NB + 4 image rows staged
#define LDSW 257                    // +1 pad: mixed-parity gather banks
#define VECS_PER_BAND 1134          // 126 patches * 36 floats / 4
#define NITER 5                     // ceil(1134/256); n=4 valid iff t<110

typedef float fvec4 __attribute__((ext_vector_type(4)));

__global__ __launch_bounds__(256) void image2patch_kernel(
    const float* __restrict__ x, float* __restrict__ out) {
  __shared__ float tile[TROWS * LDSW];   // 16.4 KB

  const int blk = blockIdx.x;            // b * 21 + g
  const int b = blk / NGROUPS;
  const int g = blk - b * NGROUPS;
  const int i0 = g * NB;
  const int t = threadIdx.x;

  // ---- stage image rows 12g..12g+15: thread t = column t of every row ----
  // per wave: 64 consecutive floats per row (coalesced); LDS bank = lane%32.
  const float* src = x + (size_t)b * (IMG * IMG) + (size_t)(12 * g) * IMG;
  #pragma unroll
  for (int w = 0; w < TROWS; ++w) {
    tile[w * LDSW + t] = src[w * IMG + t];
  }

  // ---- precompute gather offsets: band-independent, amortized over 6 bands
  int off[NITER][4];
  #pragma unroll
  for (int n = 0; n < NITER; ++n) {
    const int q = t + n * 256;          // output float4 index within a band
    const int j = q / 9;                // patch column (9 float4 per patch)
    const int s = q - 9 * j;
    const int k0 = 4 * s;
    #pragma unroll
    for (int m = 0; m < 4; ++m) {
      const int k = k0 + m;
      const int r = k / PSZ;
      const int c = k - PSZ * r;
      off[n][m] = r * LDSW + 2 * j + c; // float offset from band's top tile row
    }
  }

  __syncthreads();

  // ---- emit 6 bands: hot loop = 4 ds_read_b32 + 1 dwordx4 store ----
  #pragma unroll
  for (int band = 0; band < NB; ++band) {
    const float* tb = &tile[(2 * band) * LDSW];
    fvec4* outp = reinterpret_cast<fvec4*>(
        out + ((size_t)b * (NPOS * NPOS) + (size_t)(i0 + band) * NPOS) * (PSZ * PSZ));
    #pragma unroll
    for (int n = 0; n < NITER; ++n) {
      const int q = t + n * 256;
      if (q < VECS_PER_BAND) {          // only n=4 masks (t<110)
        fvec4 v;
        v.x = tb[off[n][0]];
        v.y = tb[off[n][1]];
        v.z = tb[off[n][2]];
        v.w = tb[off[n][3]];
        outp[q] = v;
      }
    }
  }
}

extern "C" void kernel_launch(void* const* d_in, const int* in_sizes, int n_in,
                              void* d_out, int out_size, void* d_ws, size_t ws_size,
                              hipStream_t stream) {
  const float* x = (const float*)d_in[0];
  float* out = (float*)d_out;
  image2patch_kernel<<<BATCHN * NGROUPS, 256, 0, stream>>>(x, out);
}

// Round 6
// 319.030 us; speedup vs baseline: 1.0160x; 1.0023x over previous
//
#include <hip/hip_runtime.h>

// image2patch: out[b, i*126+j, r*6+c] = x[b, 0, 2*i + r, 2*j + c]
// IMAGE_SIZE=256, PSIZE=6, STRIDE=2, NPOS=126, BATCH=128, fp32.
//
// R6 discriminator: every output float4 (k0=4s, s=0..8) is exactly TWO
// row-contiguous element pairs in the image (rows change at multiples of 6,
// pairs (k,k+1) with k even never straddle a row). So the gather is two
// 8B-aligned ds_read_b64 instead of four ds_read_b32 -> half the LDS
// instructions per store. Stride 258 (258/2 = 129 === 1 mod 16) spreads
// bank-pairs. Offsets hoisted (band-independent), 6 bands/block, exact
// tiling (126 = 6*21, rows 12g..12g+15 fit 256 exactly, no clamps).
// If this is neutral like R2/R4/R5, all on-chip pipes are exonerated ->
// kernel is at the 292.6MB-write memory floor, residual = harness fill.

#define IMG 256
#define PSZ 6
#define NPOS 126
#define BATCHN 128
#define NB 6                        // bands (patch-rows) per block
#define NGROUPS 21                  // 126 / 6, exact
#define TROWS 16                    // 2*NB + 4 image rows staged
#define LDSW 258                    // even pad: 8B-aligned pairs, W/2 % 16 == 1
#define VECS_PER_BAND 1134          // 126 patches * 36 floats / 4
#define NITER 5                     // ceil(1134/256); n=4 valid iff t<110

typedef float fvec4 __attribute__((ext_vector_type(4)));
typedef float fvec2 __attribute__((ext_vector_type(2)));

__global__ __launch_bounds__(256) void image2patch_kernel(
    const float* __restrict__ x, float* __restrict__ out) {
  __shared__ float tile[TROWS * LDSW];   // 16.1 KB

  const int blk = blockIdx.x;            // b * 21 + g
  const int b = blk / NGROUPS;
  const int g = blk - b * NGROUPS;
  const int i0 = g * NB;
  const int t = threadIdx.x;

  // ---- stage image rows 12g..12g+15: thread t = column t of every row ----
  // coalesced 256B/wave global reads; LDS bank = t%32 -> conflict-free.
  const float* src = x + (size_t)b * (IMG * IMG) + (size_t)(12 * g) * IMG;
  #pragma unroll
  for (int w = 0; w < TROWS; ++w) {
    tile[w * LDSW + t] = src[w * IMG + t];
  }

  // ---- hoist gather offsets: two b64 pair-offsets per float4, band-indep.
  int off0[NITER], off1[NITER];
  #pragma unroll
  for (int n = 0; n < NITER; ++n) {
    const int q = t + n * 256;          // output float4 index within a band
    const int j = q / 9;                // patch column (9 float4 per patch)
    const int s = q - 9 * j;
    const int k0 = 4 * s;               // even; pairs (k0,k0+1),(k0+2,k0+3)
    const int r0 = k0 / PSZ,       c0 = k0 - PSZ * r0;
    const int r1 = (k0 + 2) / PSZ, c1 = (k0 + 2) - PSZ * r1;
    off0[n] = r0 * LDSW + 2 * j + c0;   // even float offset -> 8B-aligned
    off1[n] = r1 * LDSW + 2 * j + c1;
  }

  __syncthreads();

  // ---- emit 6 bands: hot loop = 2 ds_read_b64 + 1 global_store_dwordx4 ----
  #pragma unroll
  for (int band = 0; band < NB; ++band) {
    const float* tb = &tile[(2 * band) * LDSW];
    fvec4* outp = reinterpret_cast<fvec4*>(
        out + ((size_t)b * (NPOS * NPOS) + (size_t)(i0 + band) * NPOS) * (PSZ * PSZ));
    #pragma unroll
    for (int n = 0; n < NITER; ++n) {
      const int q = t + n * 256;
      if (q < VECS_PER_BAND) {          // only n=4 masks (t<110)
        const fvec2 p0 = *reinterpret_cast<const fvec2*>(tb + off0[n]);
        const fvec2 p1 = *reinterpret_cast<const fvec2*>(tb + off1[n]);
        fvec4 v;
        v.x = p0.x; v.y = p0.y; v.z = p1.x; v.w = p1.y;
        outp[q] = v;
      }
    }
  }
}

extern "C" void kernel_launch(void* const* d_in, const int* in_sizes, int n_in,
                              void* d_out, int out_size, void* d_ws, size_t ws_size,
                              hipStream_t stream) {
  const float* x = (const float*)d_in[0];
  float* out = (float*)d_out;
  image2patch_kernel<<<BATCHN * NGROUPS, 256, 0, stream>>>(x, out);
}